// Round 1
// baseline (2468.594 us; speedup 1.0000x reference)
//
#include <hip/hip_runtime.h>
#include <cstdint>
#include <cstddef>

// Problem constants
#define N_ 4096
#define B_ 2
#define V_ 4
#define D_ 256
#define C_ 3
#define H_ 512

#define GT 128   // GEMM tile (M and N)
#define GK 16    // GEMM K step

// ---------------------------------------------------------------------------
// zero accumulators (ws is poisoned 0xAA before every timed call)
__global__ __launch_bounds__(64) void zero_accum_kernel(float* loss_sum, int* hm) {
    int t = threadIdx.x;
    if (t < 24) loss_sum[t] = 0.0f;
    if (t < 12) hm[t] = 0;
}

// ---------------------------------------------------------------------------
// invn[(b*V+v)*N + n] = 1 / max(||desc[b,n,v,:]||, eps)
__global__ __launch_bounds__(256) void norms_kernel(const float* __restrict__ desc,
                                                    float* __restrict__ invn) {
    int gw   = (blockIdx.x * 256 + threadIdx.x) >> 6;   // one wave per row
    int lane = threadIdx.x & 63;
    int bv = gw >> 12;            // gw / N
    int n  = gw & (N_ - 1);
    int b  = bv >> 2, v = bv & 3;
    const float* p = desc + ((size_t)(b * N_ + n) * V_ + v) * D_;
    float4 x = *(const float4*)(p + lane * 4);
    float s = x.x * x.x + x.y * x.y + x.z * x.z + x.w * x.w;
    #pragma unroll
    for (int off = 32; off >= 1; off >>= 1) s += __shfl_xor(s, off, 64);
    if (lane == 0) invn[gw] = 1.0f / fmaxf(sqrtf(s), 1e-12f);
}

// ---------------------------------------------------------------------------
// Gram: S[n][m] = sum_d desc[b,n,i,d]*desc[b,m,j,d]; also stores ST = S^T
__global__ __launch_bounds__(256) void gram_kernel(const float* __restrict__ desc,
                                                   float* __restrict__ S,
                                                   float* __restrict__ ST,
                                                   int i, int j, int b) {
    __shared__ float As[GK][GT];
    __shared__ float Bs[GK][GT];
    int tid = threadIdx.x;
    int n0 = blockIdx.x * GT, m0 = blockIdx.y * GT;
    const float* baseA = desc + (size_t)(b * N_ * V_ + i) * D_;
    const float* baseB = desc + (size_t)(b * N_ * V_ + j) * D_;
    int ty = tid >> 4, tx = tid & 15;
    float acc[8][8];
    #pragma unroll
    for (int a = 0; a < 8; a++)
        #pragma unroll
        for (int c = 0; c < 8; c++) acc[a][c] = 0.0f;

    for (int k0 = 0; k0 < D_; k0 += GK) {
        #pragma unroll
        for (int s = 0; s < 2; s++) {
            int q = tid + 256 * s;
            int r = q >> 2, dq = (q & 3) * 4;
            float4 va = *(const float4*)(baseA + (size_t)(n0 + r) * (V_ * D_) + k0 + dq);
            As[dq + 0][r] = va.x; As[dq + 1][r] = va.y; As[dq + 2][r] = va.z; As[dq + 3][r] = va.w;
            float4 vb = *(const float4*)(baseB + (size_t)(m0 + r) * (V_ * D_) + k0 + dq);
            Bs[dq + 0][r] = vb.x; Bs[dq + 1][r] = vb.y; Bs[dq + 2][r] = vb.z; Bs[dq + 3][r] = vb.w;
        }
        __syncthreads();
        #pragma unroll
        for (int kk = 0; kk < GK; kk++) {
            float4 a0 = *(const float4*)&As[kk][ty * 8];
            float4 a1 = *(const float4*)&As[kk][ty * 8 + 4];
            float4 b0 = *(const float4*)&Bs[kk][tx * 8];
            float4 b1 = *(const float4*)&Bs[kk][tx * 8 + 4];
            float av[8] = {a0.x, a0.y, a0.z, a0.w, a1.x, a1.y, a1.z, a1.w};
            float bv[8] = {b0.x, b0.y, b0.z, b0.w, b1.x, b1.y, b1.z, b1.w};
            #pragma unroll
            for (int a = 0; a < 8; a++)
                #pragma unroll
                for (int c = 0; c < 8; c++) acc[a][c] = fmaf(av[a], bv[c], acc[a][c]);
        }
        __syncthreads();
    }
    #pragma unroll
    for (int a = 0; a < 8; a++) {
        int n = n0 + ty * 8 + a;
        *(float4*)(S + (size_t)n * N_ + m0 + tx * 8) =
            make_float4(acc[a][0], acc[a][1], acc[a][2], acc[a][3]);
        *(float4*)(S + (size_t)n * N_ + m0 + tx * 8 + 4) =
            make_float4(acc[a][4], acc[a][5], acc[a][6], acc[a][7]);
    }
    #pragma unroll
    for (int c = 0; c < 8; c++) {
        int m = m0 + tx * 8 + c;
        *(float4*)(ST + (size_t)m * N_ + n0 + ty * 8) =
            make_float4(acc[0][c], acc[1][c], acc[2][c], acc[3][c]);
        *(float4*)(ST + (size_t)m * N_ + n0 + ty * 8 + 4) =
            make_float4(acc[4][c], acc[5][c], acc[6][c], acc[7][c]);
    }
}

// ---------------------------------------------------------------------------
// Z[(b*V+v)*N + n][h] = desc[b,n,v,:] @ W1[:,h] + b1[h]
__global__ __launch_bounds__(256) void zgemm_kernel(const float* __restrict__ desc,
                                                    const float* __restrict__ W1,
                                                    const float* __restrict__ b1,
                                                    float* __restrict__ Z) {
    __shared__ float As[GK][GT];
    __shared__ float Bs[GK][GT];
    int tid = threadIdx.x;
    int r0 = blockIdx.x * GT;      // flat row index (b*V+v)*N + n
    int h0 = blockIdx.y * GT;
    int bv = r0 >> 12;
    int n0 = r0 & (N_ - 1);
    int b = bv >> 2, v = bv & 3;
    const float* baseA = desc + (size_t)(b * N_ * V_ + v) * D_;
    int ty = tid >> 4, tx = tid & 15;
    float acc[8][8];
    #pragma unroll
    for (int a = 0; a < 8; a++)
        #pragma unroll
        for (int c = 0; c < 8; c++) acc[a][c] = 0.0f;

    for (int k0 = 0; k0 < D_; k0 += GK) {
        #pragma unroll
        for (int s = 0; s < 2; s++) {
            int q = tid + 256 * s;
            int r = q >> 2, dq = (q & 3) * 4;
            float4 va = *(const float4*)(baseA + (size_t)(n0 + r) * (V_ * D_) + k0 + dq);
            As[dq + 0][r] = va.x; As[dq + 1][r] = va.y; As[dq + 2][r] = va.z; As[dq + 3][r] = va.w;
            int kd = q >> 5, hq = (q & 31) * 4;
            *(float4*)&Bs[kd][hq] = *(const float4*)(W1 + (size_t)(k0 + kd) * H_ + h0 + hq);
        }
        __syncthreads();
        #pragma unroll
        for (int kk = 0; kk < GK; kk++) {
            float4 a0 = *(const float4*)&As[kk][ty * 8];
            float4 a1 = *(const float4*)&As[kk][ty * 8 + 4];
            float4 b0 = *(const float4*)&Bs[kk][tx * 8];
            float4 b1v = *(const float4*)&Bs[kk][tx * 8 + 4];
            float av[8] = {a0.x, a0.y, a0.z, a0.w, a1.x, a1.y, a1.z, a1.w};
            float bw[8] = {b0.x, b0.y, b0.z, b0.w, b1v.x, b1v.y, b1v.z, b1v.w};
            #pragma unroll
            for (int a = 0; a < 8; a++)
                #pragma unroll
                for (int c = 0; c < 8; c++) acc[a][c] = fmaf(av[a], bw[c], acc[a][c]);
        }
        __syncthreads();
    }
    #pragma unroll
    for (int a = 0; a < 8; a++) {
        int rr = r0 + ty * 8 + a;
        int h = h0 + tx * 8;
        *(float4*)(Z + (size_t)rr * H_ + h) =
            make_float4(acc[a][0] + b1[h + 0], acc[a][1] + b1[h + 1],
                        acc[a][2] + b1[h + 2], acc[a][3] + b1[h + 3]);
        *(float4*)(Z + (size_t)rr * H_ + h + 4) =
            make_float4(acc[a][4] + b1[h + 4], acc[a][5] + b1[h + 5],
                        acc[a][6] + b1[h + 6], acc[a][7] + b1[h + 7]);
    }
}

// ---------------------------------------------------------------------------
// tcode[dp][h] = concat(T[i].ravel(), T[j].ravel()) @ Wt[:,h]
__global__ __launch_bounds__(512) void tcode_kernel(const float* __restrict__ T,
                                                    const float* __restrict__ Wt,
                                                    float* __restrict__ tcode) {
    int dp = blockIdx.x;
    int i = dp / 3, rem = dp % 3;
    int j = rem + (rem >= i ? 1 : 0);
    int h = threadIdx.x;
    float acc = 0.0f;
    #pragma unroll
    for (int k = 0; k < 16; k++) acc = fmaf(T[i * 16 + k], Wt[k * H_ + h], acc);
    #pragma unroll
    for (int k = 0; k < 16; k++) acc = fmaf(T[j * 16 + k], Wt[(16 + k) * H_ + h], acc);
    tcode[dp * H_ + h] = acc;
}

// ---------------------------------------------------------------------------
// Row reduction over a 4096x4096 matrix: online softmax with 3 sf-weighted
// sums, plus argmax of row*invnC (column scale).  One block per row.
__global__ __launch_bounds__(256) void rowred_kernel(const float* __restrict__ Sm,
                                                     const float* __restrict__ sfv,   // + m*(V*C)
                                                     const float* __restrict__ invnC, // [m]
                                                     float* __restrict__ soft_out,    // [n][C]
                                                     int* __restrict__ idx_out) {
    int n = blockIdx.x;
    int tid = threadIdx.x;
    const float* row = Sm + (size_t)n * N_;
    float M = -INFINITY, sum = 0.f, w0 = 0.f, w1 = 0.f, w2 = 0.f;
    float bestv = -INFINITY; int besti = N_;
    for (int m = tid; m < N_; m += 256) {
        float s = row[m];
        const float* sfp = sfv + (size_t)m * (V_ * C_);
        float f0 = sfp[0], f1 = sfp[1], f2 = sfp[2];
        if (s <= M) {
            float e = __expf(s - M);
            sum += e;
            w0 = fmaf(e, f0, w0); w1 = fmaf(e, f1, w1); w2 = fmaf(e, f2, w2);
        } else {
            float rr = __expf(M - s);
            sum = fmaf(sum, rr, 1.0f);
            w0 = fmaf(w0, rr, f0); w1 = fmaf(w1, rr, f1); w2 = fmaf(w2, rr, f2);
            M = s;
        }
        float vs = s * invnC[m];
        if (vs > bestv || (vs == bestv && m < besti)) { bestv = vs; besti = m; }
    }
    __shared__ float rM[256], rS[256], rW0[256], rW1[256], rW2[256], rAV[256];
    __shared__ int rAI[256];
    rM[tid] = M; rS[tid] = sum; rW0[tid] = w0; rW1[tid] = w1; rW2[tid] = w2;
    rAV[tid] = bestv; rAI[tid] = besti;
    __syncthreads();
    for (int s2 = 128; s2 > 0; s2 >>= 1) {
        if (tid < s2) {
            float Ma = rM[tid], Mb = rM[tid + s2];
            float sa = rS[tid], sb = rS[tid + s2];
            float a0 = rW0[tid], a1 = rW1[tid], a2 = rW2[tid];
            float b0 = rW0[tid + s2], b1v = rW1[tid + s2], b2v = rW2[tid + s2];
            if (Mb > Ma) {
                float e = __expf(Ma - Mb);
                rM[tid] = Mb;
                rS[tid] = fmaf(sa, e, sb);
                rW0[tid] = fmaf(a0, e, b0); rW1[tid] = fmaf(a1, e, b1v); rW2[tid] = fmaf(a2, e, b2v);
            } else {
                float e = __expf(Mb - Ma);
                rS[tid] = fmaf(sb, e, sa);
                rW0[tid] = fmaf(b0, e, a0); rW1[tid] = fmaf(b1v, e, a1); rW2[tid] = fmaf(b2v, e, a2);
            }
            float av = rAV[tid], bvv = rAV[tid + s2];
            int ai = rAI[tid], bi = rAI[tid + s2];
            if (bvv > av || (bvv == av && bi < ai)) { rAV[tid] = bvv; rAI[tid] = bi; }
        }
        __syncthreads();
    }
    if (tid == 0) {
        float inv = 1.0f / rS[0];
        soft_out[(size_t)n * C_ + 0] = rW0[0] * inv;
        soft_out[(size_t)n * C_ + 1] = rW1[0] * inv;
        soft_out[(size_t)n * C_ + 2] = rW2[0] * inv;
        idx_out[n] = rAI[0];
    }
}

// ---------------------------------------------------------------------------
__global__ __launch_bounds__(256) void mutual_kernel(const int* __restrict__ idxA,
                                                     const int* __restrict__ idxB,
                                                     int* __restrict__ flag) {
    int n = blockIdx.x * 256 + threadIdx.x;
    int a = idxA[n];
    int ok = (idxB[a] == n) ? 1 : 0;
    unsigned long long m = __ballot(ok);
    if ((threadIdx.x & 63) == 0 && m != 0ull) atomicOr(flag, 1);
}

// ---------------------------------------------------------------------------
// Per-direction reconstruction loss: sum_n sum_c (relu(Z+tcode)@W2 + b2 - soft)^2
__global__ __launch_bounds__(256) void loss_kernel(const float* __restrict__ Z,
                                                   const float* __restrict__ tcode,
                                                   const float* __restrict__ soft,
                                                   const float* __restrict__ W2,
                                                   const float* __restrict__ b2,
                                                   float* __restrict__ loss_sum) {
    int dd = blockIdx.y;            // dp*2 + b
    int dp = dd >> 1, b = dd & 1;
    int i = dp / 3;                 // source view
    const float* tc = tcode + (size_t)dp * H_;
    const float* zbase = Z + (size_t)((b * V_ + i) * N_) * H_;
    const float* softb = soft + (size_t)dd * N_ * C_;
    int tid = threadIdx.x;
    int wid = tid >> 6, lane = tid & 63;
    __shared__ float wsum[4];
    float sse_acc = 0.0f;
    float4 t1 = *(const float4*)(tc + lane * 4);
    float4 t2 = *(const float4*)(tc + 256 + lane * 4);
    for (int rr = wid; rr < 64; rr += 4) {
        int n = blockIdx.x * 64 + rr;
        const float* zp = zbase + (size_t)n * H_;
        float4 z1 = *(const float4*)(zp + lane * 4);
        float4 z2 = *(const float4*)(zp + 256 + lane * 4);
        float pre[8] = {z1.x + t1.x, z1.y + t1.y, z1.z + t1.z, z1.w + t1.w,
                        z2.x + t2.x, z2.y + t2.y, z2.z + t2.z, z2.w + t2.w};
        float c0 = 0.f, c1 = 0.f, c2 = 0.f;
        int h1 = lane * 4, h2 = 256 + lane * 4;
        #pragma unroll
        for (int q = 0; q < 8; q++) {
            float rv = fmaxf(pre[q], 0.0f);
            int h = (q < 4) ? (h1 + q) : (h2 + q - 4);
            c0 = fmaf(rv, W2[h * 3 + 0], c0);
            c1 = fmaf(rv, W2[h * 3 + 1], c1);
            c2 = fmaf(rv, W2[h * 3 + 2], c2);
        }
        #pragma unroll
        for (int off = 32; off >= 1; off >>= 1) {
            c0 += __shfl_xor(c0, off, 64);
            c1 += __shfl_xor(c1, off, 64);
            c2 += __shfl_xor(c2, off, 64);
        }
        if (lane == 0) {
            float e0 = c0 + b2[0] - softb[(size_t)n * C_ + 0];
            float e1 = c1 + b2[1] - softb[(size_t)n * C_ + 1];
            float e2 = c2 + b2[2] - softb[(size_t)n * C_ + 2];
            sse_acc += e0 * e0 + e1 * e1 + e2 * e2;
        }
    }
    if (lane == 0) wsum[wid] = sse_acc;
    __syncthreads();
    if (tid == 0) {
        atomicAdd(&loss_sum[dd], wsum[0] + wsum[1] + wsum[2] + wsum[3]);
    }
}

// ---------------------------------------------------------------------------
__global__ __launch_bounds__(64) void final_kernel(const float* __restrict__ loss_sum,
                                                   const int* __restrict__ hm,
                                                   float* __restrict__ out) {
    if (threadIdx.x != 0 || blockIdx.x != 0) return;
    float lt = 0.0f, cnt = 0.0f;
    for (int dp = 0; dp < 12; dp++) {
        int i = dp / 3, rem = dp % 3;
        int j = rem + (rem >= i ? 1 : 0);
        int a = i < j ? i : j, c = i < j ? j : i;
        int p = a * 3 - (a * (a - 1)) / 2 + (c - a - 1);
        for (int b = 0; b < 2; b++) {
            if (hm[p * 2 + b]) {
                lt += loss_sum[dp * 2 + b] * (1.0f / ((float)N_ * (float)C_));
                cnt += 1.0f;
            }
        }
    }
    out[0] = (cnt > 0.0f) ? (lt / cnt) : 0.0f;
}

// ---------------------------------------------------------------------------
extern "C" void kernel_launch(void* const* d_in, const int* in_sizes, int n_in,
                              void* d_out, int out_size, void* d_ws, size_t ws_size,
                              hipStream_t stream) {
    const float* desc = (const float*)d_in[0];
    const float* sf   = (const float*)d_in[1];
    const float* T    = (const float*)d_in[2];
    const float* W1   = (const float*)d_in[3];
    const float* b1   = (const float*)d_in[4];
    const float* Wt   = (const float*)d_in[5];
    const float* W2   = (const float*)d_in[6];
    const float* b2   = (const float*)d_in[7];
    float* out = (float*)d_out;

    float* w = (float*)d_ws;
    // workspace layout (floats)
    const size_t NM = (size_t)N_ * N_;           // 16,777,216
    float* S     = w;                            // NM
    float* ST    = w + NM;                       // NM
    float* Z     = w + 2 * NM;                   // B*V*N*H = NM
    float* invn  = w + 3 * NM;                   // B*V*N = 32768
    float* tcode = invn + (size_t)B_ * V_ * N_;  // 12*H = 6144
    float* soft  = tcode + 12 * H_;              // 12*B*N*C = 294912
    int*   idxA  = (int*)(soft + (size_t)12 * B_ * N_ * C_);  // N
    int*   idxB  = idxA + N_;                    // N
    float* loss_sum = (float*)(idxB + N_);       // 24
    int*   hm    = (int*)(loss_sum + 24);        // 12

    zero_accum_kernel<<<1, 64, 0, stream>>>(loss_sum, hm);
    norms_kernel<<<(B_ * V_ * N_) / 4, 256, 0, stream>>>(desc, invn);
    zgemm_kernel<<<dim3((B_ * V_ * N_) / GT, H_ / GT), 256, 0, stream>>>(desc, W1, b1, Z);
    tcode_kernel<<<12, 512, 0, stream>>>(T, Wt, tcode);

    const int pairs[6][2] = {{0, 1}, {0, 2}, {0, 3}, {1, 2}, {1, 3}, {2, 3}};
    for (int p = 0; p < 6; p++) {
        int i = pairs[p][0], j = pairs[p][1];
        int dp_ij = i * 3 + (j - 1);   // j > i
        int dp_ji = j * 3 + i;         // i < j
        for (int b = 0; b < 2; b++) {
            gram_kernel<<<dim3(N_ / GT, N_ / GT), 256, 0, stream>>>(desc, S, ST, i, j, b);
            rowred_kernel<<<N_, 256, 0, stream>>>(
                S,
                sf + ((size_t)b * N_ * V_ + j) * C_,
                invn + (size_t)(b * V_ + j) * N_,
                soft + (size_t)(dp_ij * 2 + b) * N_ * C_,
                idxA);
            rowred_kernel<<<N_, 256, 0, stream>>>(
                ST,
                sf + ((size_t)b * N_ * V_ + i) * C_,
                invn + (size_t)(b * V_ + i) * N_,
                soft + (size_t)(dp_ji * 2 + b) * N_ * C_,
                idxB);
            mutual_kernel<<<16, 256, 0, stream>>>(idxA, idxB, hm + p * 2 + b);
        }
    }

    loss_kernel<<<dim3(64, 24), 256, 0, stream>>>(Z, tcode, soft, W2, b2, loss_sum);
    final_kernel<<<1, 64, 0, stream>>>(loss_sum, hm, out);
}

// Round 3
// 1840.068 us; speedup vs baseline: 1.3416x; 1.3416x over previous
//
#include <hip/hip_runtime.h>
#include <cstdint>
#include <cstddef>

// Problem constants
#define N_ 4096
#define B_ 2
#define V_ 4
#define D_ 256
#define C_ 3
#define H_ 512

#define PLANE 1048576   // N_*D_ elements per split plane
#define WPLANE 131072   // H_*D_ elements per W1T split plane

typedef __attribute__((ext_vector_type(8))) short bf16x8;   // 8 bf16 in 4 VGPRs
typedef __attribute__((ext_vector_type(4))) float f32x4;

// ---------------------------------------------------------------------------
__device__ __forceinline__ void gload16(const void* g, void* l) {
    __builtin_amdgcn_global_load_lds(
        (const __attribute__((address_space(1))) void*)g,
        (__attribute__((address_space(3))) void*)l,
        16, 0, 0);
}

// RNE float->bf16 (no NaN handling needed for this data)
__device__ __forceinline__ unsigned short f2bf(float x) {
    unsigned u = __builtin_bit_cast(unsigned, x);
    u += 0x7FFFu + ((u >> 16) & 1u);
    return (unsigned short)(u >> 16);
}
__device__ __forceinline__ float bf2f(unsigned short h) {
    unsigned u = ((unsigned)h) << 16;
    return __builtin_bit_cast(float, u);
}

__device__ __forceinline__ void split3(float x, unsigned short& h, unsigned short& m,
                                       unsigned short& l) {
    h = f2bf(x);
    float r = x - bf2f(h);
    m = f2bf(r);
    l = f2bf(r - bf2f(m));
}

// ---------------------------------------------------------------------------
__global__ __launch_bounds__(64) void zero_accum_kernel(float* loss_sum, int* hm) {
    int t = threadIdx.x;
    if (t < 24) loss_sum[t] = 0.0f;
    if (t < 12) hm[t] = 0;
}

// ---------------------------------------------------------------------------
// Split desc fp32 -> 3 bf16 planes per (b,v):  SP[(bv*3+l)][n][d]
__global__ __launch_bounds__(256) void split_kernel(const float* __restrict__ desc,
                                                    unsigned short* __restrict__ SP) {
    int t = blockIdx.x * 256 + threadIdx.x;     // 2,097,152 threads
    int d4 = t & 63;
    int v  = (t >> 6) & 3;
    int n  = (t >> 8) & 4095;
    int b  = t >> 20;
    const float4 x = *(const float4*)(desc + (((size_t)(b * N_ + n) * V_ + v) << 8) + d4 * 4);
    ushort4 hv, mv, lv;
    split3(x.x, hv.x, mv.x, lv.x);
    split3(x.y, hv.y, mv.y, lv.y);
    split3(x.z, hv.z, mv.z, lv.z);
    split3(x.w, hv.w, mv.w, lv.w);
    size_t base = (size_t)((b * V_ + v) * 3) * PLANE + n * D_ + d4 * 4;
    *(ushort4*)(SP + base)              = hv;
    *(ushort4*)(SP + base + PLANE)      = mv;
    *(ushort4*)(SP + base + 2 * PLANE)  = lv;
}

// W1 [D][H] -> transposed split planes W1T[l][h][k]
__global__ __launch_bounds__(256) void w1split_kernel(const float* __restrict__ W1,
                                                      unsigned short* __restrict__ W1T) {
    int t = blockIdx.x * 256 + threadIdx.x;     // 131072
    int h = t & 511;
    int k = t >> 9;
    float x = W1[(size_t)k * H_ + h];
    unsigned short hv, mv, lv;
    split3(x, hv, mv, lv);
    size_t o = (size_t)h * D_ + k;
    W1T[o] = hv; W1T[o + WPLANE] = mv; W1T[o + 2 * WPLANE] = lv;
}

// ---------------------------------------------------------------------------
// invn[(b*V+v)*N + n] = 1 / max(||desc[b,n,v,:]||, eps)
__global__ __launch_bounds__(256) void norms_kernel(const float* __restrict__ desc,
                                                    float* __restrict__ invn) {
    int gw   = (blockIdx.x * 256 + threadIdx.x) >> 6;
    int lane = threadIdx.x & 63;
    int bv = gw >> 12;
    int n  = gw & (N_ - 1);
    int b  = bv >> 2, v = bv & 3;
    const float* p = desc + ((size_t)(b * N_ + n) * V_ + v) * D_;
    float4 x = *(const float4*)(p + lane * 4);
    float s = x.x * x.x + x.y * x.y + x.z * x.z + x.w * x.w;
    #pragma unroll
    for (int off = 32; off >= 1; off >>= 1) s += __shfl_xor(s, off, 64);
    if (lane == 0) invn[gw] = 1.0f / fmaxf(sqrtf(s), 1e-12f);
}

// ---------------------------------------------------------------------------
// bf16x6 emulated-fp32 GEMM body: C[128x128 tile] = A-rows x B-rows^T, K=256.
// A/B planes row-major [rows][256] bf16 (hi/mid/lo).  m97-style structure:
// BK=32, global_load_lds width 16, 4 waves each owning a 64x64 subtile.
// 6 product passes: hh, hm, mh, hl, lh, mm  (al+bl<=2)  -> ~2^-24 rel error.
template<bool TRANS, bool BIAS>
__device__ __forceinline__ void mm6_body(
    const unsigned short* __restrict__ A0, const unsigned short* __restrict__ A1,
    const unsigned short* __restrict__ A2,
    const unsigned short* __restrict__ B0, const unsigned short* __restrict__ B1,
    const unsigned short* __restrict__ B2,
    int bx, int by,
    float* __restrict__ Cout, float* __restrict__ CTout,
    const float* __restrict__ bias, int ldc,
    unsigned short* smem) {
    const int tid = threadIdx.x;
    const int wid = tid >> 6, lane = tid & 63;
    const int wr = wid >> 1, wc = wid & 1;
    const int arow0 = bx * 128, brow0 = by * 128;

    f32x4 acc[4][4];
    #pragma unroll
    for (int m = 0; m < 4; ++m)
        #pragma unroll
        for (int n = 0; n < 4; ++n) acc[m][n] = (f32x4){0.f, 0.f, 0.f, 0.f};

    const unsigned short* Asrc[3] = {A0, A1, A2};
    const unsigned short* Bsrc[3] = {B0, B1, B2};
    const int q    = wid * 2;            // chunk base (each chunk = 16 rows = 1KB)
    const int srow = lane >> 2;          // 0..15
    const int scol = (lane & 3) * 8;     // element offset (8 bf16 = 16B)

    const int fr = lane & 15;            // fragment row/col within 16
    const int fk = (lane >> 4) * 8;      // k sub-chunk

    for (int k0 = 0; k0 < D_; k0 += 32) {
        __syncthreads();
        #pragma unroll
        for (int p = 0; p < 6; ++p) {
            const unsigned short* src = (p < 3) ? Asrc[p] : Bsrc[p - 3];
            const int r0 = (p < 3) ? arow0 : brow0;
            unsigned short* ldsb = smem + p * 4096 + q * 512;
            #pragma unroll
            for (int c = 0; c < 2; ++c) {
                const unsigned short* g =
                    src + ((size_t)(r0 + (q + c) * 16 + srow) << 8) + k0 + scol;
                gload16(g, ldsb + c * 512);
            }
        }
        __syncthreads();

        bf16x8 af[3][4];
        #pragma unroll
        for (int l = 0; l < 3; ++l)
            #pragma unroll
            for (int m = 0; m < 4; ++m)
                af[l][m] = *(const bf16x8*)(smem + l * 4096 +
                                            (wr * 64 + m * 16 + fr) * 32 + fk);
        #pragma unroll
        for (int bl = 0; bl < 3; ++bl) {
            bf16x8 bfr[4];
            #pragma unroll
            for (int n = 0; n < 4; ++n)
                bfr[n] = *(const bf16x8*)(smem + (3 + bl) * 4096 +
                                          (wc * 64 + n * 16 + fr) * 32 + fk);
            #pragma unroll
            for (int al = 0; al < 3; ++al) {
                if (al + bl > 2) continue;
                #pragma unroll
                for (int m = 0; m < 4; ++m)
                    #pragma unroll
                    for (int n = 0; n < 4; ++n)
                        acc[m][n] = __builtin_amdgcn_mfma_f32_16x16x32_bf16(
                            af[al][m], bfr[n], acc[m][n], 0, 0, 0);
            }
        }
    }

    // epilogue: C/D layout col=lane&15, row=(lane>>4)*4+reg  [m89-verified]
    const int crow = (lane >> 4) * 4;
    const int ccol = lane & 15;
    #pragma unroll
    for (int m = 0; m < 4; ++m) {
        const int gr = arow0 + wr * 64 + m * 16 + crow;
        #pragma unroll
        for (int n = 0; n < 4; ++n) {
            const int gc = brow0 + wc * 64 + n * 16 + ccol;
            f32x4 v = acc[m][n];
            float bv = BIAS ? bias[gc] : 0.0f;
            #pragma unroll
            for (int r = 0; r < 4; ++r)
                Cout[(size_t)(gr + r) * ldc + gc] = v[r] + bv;
            if (TRANS)
                *(f32x4*)&CTout[(size_t)gc * ldc + gr] = v;
        }
    }
}

// Gram: S = desc_i . desc_j^T (and ST = S^T), via plane groups gA,gB (= b*V+v)
__global__ __launch_bounds__(256) void gram6_kernel(const unsigned short* __restrict__ SP,
                                                    int gA, int gB,
                                                    float* __restrict__ S,
                                                    float* __restrict__ ST) {
    __shared__ unsigned short smem[6 * 4096];
    int bid = blockIdx.y * gridDim.x + blockIdx.x;     // 0..1023
    int swz = (bid & 7) * 128 + (bid >> 3);            // XCD-bijective (1024%8==0)
    int bx = swz & 31, by = swz >> 5;
    mm6_body<true, false>(SP + (size_t)(gA * 3 + 0) * PLANE,
                          SP + (size_t)(gA * 3 + 1) * PLANE,
                          SP + (size_t)(gA * 3 + 2) * PLANE,
                          SP + (size_t)(gB * 3 + 0) * PLANE,
                          SP + (size_t)(gB * 3 + 1) * PLANE,
                          SP + (size_t)(gB * 3 + 2) * PLANE,
                          bx, by, S, ST, nullptr, N_, smem);
}

// Z[bv*N + n][h] = desc(bv) @ W1 + b1
__global__ __launch_bounds__(256) void zmm6_kernel(const unsigned short* __restrict__ SP,
                                                   const unsigned short* __restrict__ W1T,
                                                   const float* __restrict__ b1,
                                                   float* __restrict__ Z) {
    __shared__ unsigned short smem[6 * 4096];
    int bv = blockIdx.z;
    mm6_body<false, true>(SP + (size_t)(bv * 3 + 0) * PLANE,
                          SP + (size_t)(bv * 3 + 1) * PLANE,
                          SP + (size_t)(bv * 3 + 2) * PLANE,
                          W1T, W1T + WPLANE, W1T + 2 * WPLANE,
                          blockIdx.x, blockIdx.y,
                          Z + (size_t)bv * N_ * H_, nullptr, b1, H_, smem);
}

// ---------------------------------------------------------------------------
// tcode[dp][h] = concat(T[i].ravel(), T[j].ravel()) @ Wt[:,h]
__global__ __launch_bounds__(512) void tcode_kernel(const float* __restrict__ T,
                                                    const float* __restrict__ Wt,
                                                    float* __restrict__ tcode) {
    int dp = blockIdx.x;
    int i = dp / 3, rem = dp % 3;
    int j = rem + (rem >= i ? 1 : 0);
    int h = threadIdx.x;
    float acc = 0.0f;
    #pragma unroll
    for (int k = 0; k < 16; k++) acc = fmaf(T[i * 16 + k], Wt[k * H_ + h], acc);
    #pragma unroll
    for (int k = 0; k < 16; k++) acc = fmaf(T[j * 16 + k], Wt[(16 + k) * H_ + h], acc);
    tcode[dp * H_ + h] = acc;
}

// ---------------------------------------------------------------------------
// Row reduction: online softmax + 3 sf-weighted sums + scaled argmax.
__global__ __launch_bounds__(256) void rowred_kernel(const float* __restrict__ Sm,
                                                     const float* __restrict__ sfv,
                                                     const float* __restrict__ invnC,
                                                     float* __restrict__ soft_out,
                                                     int* __restrict__ idx_out) {
    int n = blockIdx.x;
    int tid = threadIdx.x;
    const float* row = Sm + (size_t)n * N_;
    float M = -INFINITY, sum = 0.f, w0 = 0.f, w1 = 0.f, w2 = 0.f;
    float bestv = -INFINITY; int besti = N_;
    for (int m = tid; m < N_; m += 256) {
        float s = row[m];
        const float* sfp = sfv + (size_t)m * (V_ * C_);
        float f0 = sfp[0], f1 = sfp[1], f2 = sfp[2];
        if (s <= M) {
            float e = __expf(s - M);
            sum += e;
            w0 = fmaf(e, f0, w0); w1 = fmaf(e, f1, w1); w2 = fmaf(e, f2, w2);
        } else {
            float rr = __expf(M - s);
            sum = fmaf(sum, rr, 1.0f);
            w0 = fmaf(w0, rr, f0); w1 = fmaf(w1, rr, f1); w2 = fmaf(w2, rr, f2);
            M = s;
        }
        float vs = s * invnC[m];
        if (vs > bestv || (vs == bestv && m < besti)) { bestv = vs; besti = m; }
    }
    __shared__ float rM[256], rS[256], rW0[256], rW1[256], rW2[256], rAV[256];
    __shared__ int rAI[256];
    rM[tid] = M; rS[tid] = sum; rW0[tid] = w0; rW1[tid] = w1; rW2[tid] = w2;
    rAV[tid] = bestv; rAI[tid] = besti;
    __syncthreads();
    for (int s2 = 128; s2 > 0; s2 >>= 1) {
        if (tid < s2) {
            float Ma = rM[tid], Mb = rM[tid + s2];
            float sa = rS[tid], sb = rS[tid + s2];
            float a0 = rW0[tid], a1 = rW1[tid], a2 = rW2[tid];
            float b0 = rW0[tid + s2], b1v = rW1[tid + s2], b2v = rW2[tid + s2];
            if (Mb > Ma) {
                float e = __expf(Ma - Mb);
                rM[tid] = Mb;
                rS[tid] = fmaf(sa, e, sb);
                rW0[tid] = fmaf(a0, e, b0); rW1[tid] = fmaf(a1, e, b1v); rW2[tid] = fmaf(a2, e, b2v);
            } else {
                float e = __expf(Mb - Ma);
                rS[tid] = fmaf(sb, e, sa);
                rW0[tid] = fmaf(b0, e, a0); rW1[tid] = fmaf(b1v, e, a1); rW2[tid] = fmaf(b2v, e, a2);
            }
            float av = rAV[tid], bvv = rAV[tid + s2];
            int ai = rAI[tid], bi = rAI[tid + s2];
            if (bvv > av || (bvv == av && bi < ai)) { rAV[tid] = bvv; rAI[tid] = bi; }
        }
        __syncthreads();
    }
    if (tid == 0) {
        float inv = 1.0f / rS[0];
        soft_out[(size_t)n * C_ + 0] = rW0[0] * inv;
        soft_out[(size_t)n * C_ + 1] = rW1[0] * inv;
        soft_out[(size_t)n * C_ + 2] = rW2[0] * inv;
        idx_out[n] = rAI[0];
    }
}

// ---------------------------------------------------------------------------
__global__ __launch_bounds__(256) void mutual_kernel(const int* __restrict__ idxA,
                                                     const int* __restrict__ idxB,
                                                     int* __restrict__ flag) {
    int n = blockIdx.x * 256 + threadIdx.x;
    int a = idxA[n];
    int ok = (idxB[a] == n) ? 1 : 0;
    unsigned long long m = __ballot(ok);
    if ((threadIdx.x & 63) == 0 && m != 0ull) atomicOr(flag, 1);
}

// ---------------------------------------------------------------------------
__global__ __launch_bounds__(256) void loss_kernel(const float* __restrict__ Z,
                                                   const float* __restrict__ tcode,
                                                   const float* __restrict__ soft,
                                                   const float* __restrict__ W2,
                                                   const float* __restrict__ b2,
                                                   float* __restrict__ loss_sum) {
    int dd = blockIdx.y;
    int dp = dd >> 1, b = dd & 1;
    int i = dp / 3;
    const float* tc = tcode + (size_t)dp * H_;
    const float* zbase = Z + (size_t)((b * V_ + i) * N_) * H_;
    const float* softb = soft + (size_t)dd * N_ * C_;
    int tid = threadIdx.x;
    int wid = tid >> 6, lane = tid & 63;
    __shared__ float wsum[4];
    float sse_acc = 0.0f;
    float4 t1 = *(const float4*)(tc + lane * 4);
    float4 t2 = *(const float4*)(tc + 256 + lane * 4);
    for (int rr = wid; rr < 64; rr += 4) {
        int n = blockIdx.x * 64 + rr;
        const float* zp = zbase + (size_t)n * H_;
        float4 z1 = *(const float4*)(zp + lane * 4);
        float4 z2 = *(const float4*)(zp + 256 + lane * 4);
        float pre[8] = {z1.x + t1.x, z1.y + t1.y, z1.z + t1.z, z1.w + t1.w,
                        z2.x + t2.x, z2.y + t2.y, z2.z + t2.z, z2.w + t2.w};
        float c0 = 0.f, c1 = 0.f, c2 = 0.f;
        int h1 = lane * 4, h2 = 256 + lane * 4;
        #pragma unroll
        for (int q = 0; q < 8; q++) {
            float rv = fmaxf(pre[q], 0.0f);
            int h = (q < 4) ? (h1 + q) : (h2 + q - 4);
            c0 = fmaf(rv, W2[h * 3 + 0], c0);
            c1 = fmaf(rv, W2[h * 3 + 1], c1);
            c2 = fmaf(rv, W2[h * 3 + 2], c2);
        }
        #pragma unroll
        for (int off = 32; off >= 1; off >>= 1) {
            c0 += __shfl_xor(c0, off, 64);
            c1 += __shfl_xor(c1, off, 64);
            c2 += __shfl_xor(c2, off, 64);
        }
        if (lane == 0) {
            float e0 = c0 + b2[0] - softb[(size_t)n * C_ + 0];
            float e1 = c1 + b2[1] - softb[(size_t)n * C_ + 1];
            float e2 = c2 + b2[2] - softb[(size_t)n * C_ + 2];
            sse_acc += e0 * e0 + e1 * e1 + e2 * e2;
        }
    }
    if (lane == 0) wsum[wid] = sse_acc;
    __syncthreads();
    if (tid == 0) {
        atomicAdd(&loss_sum[dd], wsum[0] + wsum[1] + wsum[2] + wsum[3]);
    }
}

// ---------------------------------------------------------------------------
__global__ __launch_bounds__(64) void final_kernel(const float* __restrict__ loss_sum,
                                                   const int* __restrict__ hm,
                                                   float* __restrict__ out) {
    if (threadIdx.x != 0 || blockIdx.x != 0) return;
    float lt = 0.0f, cnt = 0.0f;
    for (int dp = 0; dp < 12; dp++) {
        int i = dp / 3, rem = dp % 3;
        int j = rem + (rem >= i ? 1 : 0);
        int a = i < j ? i : j, c = i < j ? j : i;
        int p = a * 3 - (a * (a - 1)) / 2 + (c - a - 1);
        for (int b = 0; b < 2; b++) {
            if (hm[p * 2 + b]) {
                lt += loss_sum[dp * 2 + b] * (1.0f / ((float)N_ * (float)C_));
                cnt += 1.0f;
            }
        }
    }
    out[0] = (cnt > 0.0f) ? (lt / cnt) : 0.0f;
}

// ---------------------------------------------------------------------------
extern "C" void kernel_launch(void* const* d_in, const int* in_sizes, int n_in,
                              void* d_out, int out_size, void* d_ws, size_t ws_size,
                              hipStream_t stream) {
    const float* desc = (const float*)d_in[0];
    const float* sf   = (const float*)d_in[1];
    const float* T    = (const float*)d_in[2];
    const float* W1   = (const float*)d_in[3];
    const float* b1   = (const float*)d_in[4];
    const float* Wt   = (const float*)d_in[5];
    const float* W2   = (const float*)d_in[6];
    const float* b2   = (const float*)d_in[7];
    float* out = (float*)d_out;

    // workspace layout (SP first for 16B alignment)
    const size_t NM = (size_t)N_ * N_;                    // 16,777,216
    unsigned short* SP  = (unsigned short*)d_ws;          // 24 planes * PLANE (50.3MB)
    unsigned short* W1T = SP + (size_t)24 * PLANE;        // 3 * WPLANE (0.79MB)
    float* w    = (float*)(W1T + (size_t)3 * WPLANE);
    float* S    = w;                                      // NM
    float* ST   = w + NM;                                 // NM
    float* Z    = w + 2 * NM;                             // B*V*N*H = NM
    float* invn = w + 3 * NM;                             // 32768
    float* tcode = invn + (size_t)B_ * V_ * N_;           // 6144
    float* soft  = tcode + 12 * H_;                       // 294912
    int*   idxA  = (int*)(soft + (size_t)12 * B_ * N_ * C_);
    int*   idxB  = idxA + N_;
    float* loss_sum = (float*)(idxB + N_);
    int*   hm    = (int*)(loss_sum + 24);

    zero_accum_kernel<<<1, 64, 0, stream>>>(loss_sum, hm);
    split_kernel<<<8192, 256, 0, stream>>>(desc, SP);
    w1split_kernel<<<512, 256, 0, stream>>>(W1, W1T);
    norms_kernel<<<(B_ * V_ * N_) / 4, 256, 0, stream>>>(desc, invn);
    zmm6_kernel<<<dim3(32, 4, 8), 256, 0, stream>>>(SP, W1T, b1, Z);
    tcode_kernel<<<12, 512, 0, stream>>>(T, Wt, tcode);

    const int pairs[6][2] = {{0, 1}, {0, 2}, {0, 3}, {1, 2}, {1, 3}, {2, 3}};
    for (int p = 0; p < 6; p++) {
        int i = pairs[p][0], j = pairs[p][1];
        int dp_ij = i * 3 + (j - 1);   // j > i
        int dp_ji = j * 3 + i;         // i < j
        for (int b = 0; b < 2; b++) {
            gram6_kernel<<<dim3(32, 32), 256, 0, stream>>>(SP, b * V_ + i, b * V_ + j, S, ST);
            rowred_kernel<<<N_, 256, 0, stream>>>(
                S,
                sf + ((size_t)b * N_ * V_ + j) * C_,
                invn + (size_t)(b * V_ + j) * N_,
                soft + (size_t)(dp_ij * 2 + b) * N_ * C_,
                idxA);
            rowred_kernel<<<N_, 256, 0, stream>>>(
                ST,
                sf + ((size_t)b * N_ * V_ + i) * C_,
                invn + (size_t)(b * V_ + i) * N_,
                soft + (size_t)(dp_ji * 2 + b) * N_ * C_,
                idxB);
            mutual_kernel<<<16, 256, 0, stream>>>(idxA, idxB, hm + p * 2 + b);
        }
    }

    loss_kernel<<<dim3(64, 24), 256, 0, stream>>>(Z, tcode, soft, W2, b2, loss_sum);
    final_kernel<<<1, 64, 0, stream>>>(loss_sum, hm, out);
}